// Round 6
// baseline (583.792 us; speedup 1.0000x reference)
//
#include <hip/hip_runtime.h>

// AttackLSTM R21 — MFMA rec matvec, weights AGPR-native.
// R20 post-mortem: cadence 1535cy/step invariant across fdot2/pk_fma/LDS-mix
// -> serial-latency-chain bound (h LDS roundtrip + 16-deep dot chain + 2-trans
// act chain). Also LDS pipe ~94% at R20 mix yet not binding. R21 moves the
// 256x64 rec matvec to the matrix pipe: W as B-operand fragments (16 col-tiles
// x 2 K-chunks = 32 mfma_f32_16x16x32_f16, 128 AGPRs — MFMA sources AGPR
// natively, killing the arch-128 wall + copy tax for good). A-operand = h
// replicated across rows -> D[r,c] = p[16t+c] for all r. Lane mapping works
// out to hid(lane)=lane EXACTLY -> hh layout contract unchanged -> proj/b
// waves verbatim R20. Extract = 3 cndmask/gate (static reg idx). A-frags =
// 4x ds_read_b64 (k = 4*(l>>4)+j per 16-K block, per m156 tr-layout).
// Dot chain 16-deep -> 2-deep; rec VALU issue ~4x down.
// Verification: MfmaUtil > 0; WRITE_SIZE ~512KB (no spill).
// Stage schedule (epoch e): w0 a0rec@e | w4,5 a1proj@e-1 | w1 a1rec@e-2 |
// w6,7 a2proj@e-3 | w2 a2rec@e-4 | w3 b-chain@e-5.  CH=8, NS=16.

#define BB 256
#define TT 512
#define CH 8
#define NS 16  // ring slots = 2*CH

typedef _Float16 v2h __attribute__((ext_vector_type(2)));
typedef _Float16 v8h __attribute__((ext_vector_type(8)));
typedef float v4f __attribute__((ext_vector_type(4)));

__device__ __forceinline__ float sig_(float x) {
  return __builtin_amdgcn_rcpf(1.f + __builtin_amdgcn_exp2f(-1.44269504f * x));
}
__device__ __forceinline__ float tanh_(float x) {
  return __builtin_fmaf(2.f, __builtin_amdgcn_rcpf(1.f + __builtin_amdgcn_exp2f(-2.88539008f * x)), -1.f);
}

template <int K>
__device__ __forceinline__ float qb_(float v) {
  return __int_as_float(__builtin_amdgcn_update_dpp(
      0, __float_as_int(v), (K | (K << 2) | (K << 4) | (K << 6)), 0xF, 0xF, true));
}

__device__ __forceinline__ void ldsbar_() {
  asm volatile("s_waitcnt lgkmcnt(0)\n\ts_barrier" ::: "memory");
}

#if __has_builtin(__builtin_amdgcn_fdot2)
#define FDOT2(acc, a, b) (acc) = __builtin_amdgcn_fdot2((a), (b), (acc), false)
#else
#define FDOT2(acc, a, b) \
  (acc) = __builtin_fmaf((float)(a)[0], (float)(b)[0], \
          __builtin_fmaf((float)(a)[1], (float)(b)[1], (acc)))
#endif
#define KEEPP(a) asm volatile("" : "+v"(a))
#define PIN16(w)                                                            \
  do {                                                                      \
    _Pragma("unroll") for (int _i = 0; _i < 16; ++_i) KEEPP((w)[_i]);       \
  } while (0)

__device__ __forceinline__ v2h bc2h_(int v) { return __builtin_bit_cast(v2h, v); }

// 64 halfs from LDS as 32 v2h via int4 reads (8x ds_read_b128).
__device__ __forceinline__ void load_h64(const _Float16* p, v2h hv[32]) {
  const int4* hp = reinterpret_cast<const int4*>(p);
#pragma unroll
  for (int i = 0; i < 8; ++i) {
    int4 blk = hp[i];
    hv[4 * i + 0] = bc2h_(blk.x);
    hv[4 * i + 1] = bc2h_(blk.y);
    hv[4 * i + 2] = bc2h_(blk.z);
    hv[4 * i + 3] = bc2h_(blk.w);
  }
}

// fp32 row of 64 -> two 16-v2h halves (k 0..31 -> lo, k 32..63 -> hi).
__device__ __forceinline__ void load_row_pair(const float* src, v2h lo[16], v2h hi[16]) {
  const float4* p = reinterpret_cast<const float4*>(src);
#pragma unroll
  for (int i = 0; i < 8; ++i) {
    float4 v = p[i];
    lo[2 * i]     = v2h{(_Float16)v.x, (_Float16)v.y};
    lo[2 * i + 1] = v2h{(_Float16)v.z, (_Float16)v.w};
  }
#pragma unroll
  for (int i = 0; i < 8; ++i) {
    float4 v = p[8 + i];
    hi[2 * i]     = v2h{(_Float16)v.x, (_Float16)v.y};
    hi[2 * i + 1] = v2h{(_Float16)v.z, (_Float16)v.w};
  }
}

// B-fragment for tile t, K-chunk kc of W[256x64] (row-major f32).
// Lane l holds B[k, col=l&15] = W[16t+(l&15)][32kc + kmap(j)],
// kmap: j=0..3 -> 4*(l>>4)+j ; j=4..7 -> 16+4*(l>>4)+(j-4).
__device__ __forceinline__ v8h ldbfrag_(const float* W, int t, int kc, int lane) {
  const int row = 16 * t + (lane & 15);
  const float* p = W + row * 64 + 32 * kc + 4 * (lane >> 4);
  float4 fa = *reinterpret_cast<const float4*>(p);
  float4 fb = *reinterpret_cast<const float4*>(p + 16);
  return v8h{(_Float16)fa.x, (_Float16)fa.y, (_Float16)fa.z, (_Float16)fa.w,
             (_Float16)fb.x, (_Float16)fb.y, (_Float16)fb.z, (_Float16)fb.w};
}

// p[256] = W*h via 32 MFMAs; lane l gets p[64g + l] into p[g].
__device__ __forceinline__ void mfma_matvec_(const v8h bfr[16][2],
                                             const _Float16* hprev, int lane,
                                             float p[4]) {
  const char* hp = reinterpret_cast<const char*>(hprev);
  const int off = 8 * (lane >> 4);
  int2 r00 = *reinterpret_cast<const int2*>(hp + off);        // kc0, k 0..15 blk
  int2 r01 = *reinterpret_cast<const int2*>(hp + off + 32);   // kc0, k 16..31 blk
  int2 r10 = *reinterpret_cast<const int2*>(hp + off + 64);   // kc1
  int2 r11 = *reinterpret_cast<const int2*>(hp + off + 96);
  v8h A0 = __builtin_bit_cast(v8h, int4{r00.x, r00.y, r01.x, r01.y});
  v8h A1 = __builtin_bit_cast(v8h, int4{r10.x, r10.y, r11.x, r11.y});
  const v4f z = {0.f, 0.f, 0.f, 0.f};
  v4f acc[16];
#pragma unroll
  for (int t = 0; t < 16; ++t) {
    v4f d = __builtin_amdgcn_mfma_f32_16x16x32_f16(A0, bfr[t][0], z, 0, 0, 0);
    acc[t] = __builtin_amdgcn_mfma_f32_16x16x32_f16(A1, bfr[t][1], d, 0, 0, 0);
  }
  const int q = lane >> 4;
  const bool s0 = q & 1, s1 = q & 2;
#pragma unroll
  for (int g = 0; g < 4; ++g) {
    float v01 = s0 ? acc[4 * g + 1][0] : acc[4 * g + 0][0];
    float v23 = s0 ? acc[4 * g + 3][0] : acc[4 * g + 2][0];
    p[g] = s1 ? v23 : v01;
  }
}

// 2-gate proj dot over full k (gate A: wa_lo/wa_hi, gate B: wb_lo/wb_hi).
__device__ __forceinline__ void dot2g_(const v2h* wa_lo, const v2h* wa_hi,
                                       const v2h* wb_lo, const v2h* wb_hi,
                                       const v2h hv[32], float& p0, float& p1) {
  float a0 = 0.f, a1 = 0.f, b0 = 0.f, b1 = 0.f;
#pragma unroll
  for (int j = 0; j < 16; j += 2) {
    FDOT2(a0, wa_lo[j], hv[j]);          FDOT2(b0, wa_lo[j + 1], hv[j + 1]);
    FDOT2(a0, wa_hi[j], hv[16 + j]);     FDOT2(b0, wa_hi[j + 1], hv[17 + j]);
    FDOT2(a1, wb_lo[j], hv[j]);          FDOT2(b1, wb_lo[j + 1], hv[j + 1]);
    FDOT2(a1, wb_hi[j], hv[16 + j]);     FDOT2(b1, wb_hi[j + 1], hv[17 + j]);
  }
  p0 = a0 + b0; p1 = a1 + b1;
}

__global__ __attribute__((amdgpu_flat_work_group_size(512, 512),
                          amdgpu_waves_per_eu(2, 2)))
void lstm_pipe_k(
    const float* __restrict__ x,
    const float* __restrict__ wih_a0, const float* __restrict__ whh_a0,
    const float* __restrict__ bih_a0, const float* __restrict__ bhh_a0,
    const float* __restrict__ wih_a1, const float* __restrict__ whh_a1,
    const float* __restrict__ bih_a1, const float* __restrict__ bhh_a1,
    const float* __restrict__ wih_a2, const float* __restrict__ whh_a2,
    const float* __restrict__ bih_a2, const float* __restrict__ bhh_a2,
    const float* __restrict__ wih_b0, const float* __restrict__ whh_b0,
    const float* __restrict__ bih_b0, const float* __restrict__ bhh_b0,
    const float* __restrict__ wih_b1, const float* __restrict__ whh_b1,
    const float* __restrict__ bih_b1, const float* __restrict__ bhh_b1,
    const float* __restrict__ wih_b2, const float* __restrict__ whh_b2,
    const float* __restrict__ bih_b2, const float* __restrict__ bhh_b2,
    float* __restrict__ out)  // [B,T]
{
  const int b = blockIdx.x;
  const int tid = threadIdx.x;
  const int wave = tid >> 6;
  const int lane = tid & 63;

  __shared__ __align__(16) _Float16 hh[3][NS][64];  // h rings
  __shared__ __align__(16) float pj[2][NS][256];    // proj rings [hid][gate]
  __shared__ float xs[TT];

  for (int i = tid; i < TT; i += 512) xs[i] = x[(size_t)b * TT + i];
  for (int i = tid; i < 3 * NS * 64 / 2; i += 512) reinterpret_cast<int*>(hh)[i] = 0;

  v8h bfr[16][2];   // rec waves: MFMA B-fragments (AGPR-resident)
  v2h wt[4][16];    // proj/b waves: register weights (arch VGPR)
  float bias[4] = {0.f, 0.f, 0.f, 0.f};
  float wi0_[4] = {0.f, 0.f, 0.f, 0.f};
  float whb0[4] = {}, wi1b[4] = {}, wh1b[4] = {}, bb1[4] = {},
        wi2b[4] = {}, wh2b[4] = {}, bb2[4] = {};

  if (wave == 0) {  // a0 recurrence
#pragma unroll
    for (int t = 0; t < 16; ++t) {
      bfr[t][0] = ldbfrag_(whh_a0, t, 0, lane);
      bfr[t][1] = ldbfrag_(whh_a0, t, 1, lane);
    }
#pragma unroll
    for (int q = 0; q < 4; ++q) {
      const int row = q * 64 + lane;
      bias[q] = bih_a0[row] + bhh_a0[row];
      wi0_[q] = wih_a0[row];
    }
  } else if (wave == 1) {  // a1 recurrence
#pragma unroll
    for (int t = 0; t < 16; ++t) {
      bfr[t][0] = ldbfrag_(whh_a1, t, 0, lane);
      bfr[t][1] = ldbfrag_(whh_a1, t, 1, lane);
    }
#pragma unroll
    for (int q = 0; q < 4; ++q) bias[q] = bih_a1[q * 64 + lane] + bhh_a1[q * 64 + lane];
  } else if (wave == 2) {  // a2 recurrence
#pragma unroll
    for (int t = 0; t < 16; ++t) {
      bfr[t][0] = ldbfrag_(whh_a2, t, 0, lane);
      bfr[t][1] = ldbfrag_(whh_a2, t, 1, lane);
    }
#pragma unroll
    for (int q = 0; q < 4; ++q) bias[q] = bih_a2[q * 64 + lane] + bhh_a2[q * 64 + lane];
  } else if (wave == 3) {  // b-chain: one row of wih_b0 in wt[0](lo)/wt[1](hi)
    const int q = lane & 3;
    load_row_pair(wih_b0 + q * 64, wt[0], wt[1]);
    bias[0] = bih_b0[q] + bhh_b0[q];
#pragma unroll
    for (int k = 0; k < 4; ++k) {
      whb0[k] = whh_b0[k];
      wi1b[k] = wih_b1[k]; wh1b[k] = whh_b1[k]; bb1[k] = bih_b1[k] + bhh_b1[k];
      wi2b[k] = wih_b2[k]; wh2b[k] = whh_b2[k]; bb2[k] = bih_b2[k] + bhh_b2[k];
    }
    PIN16(wt[0]); PIN16(wt[1]);
  } else if (wave == 4) {  // a1 proj gates 0,1
    load_row_pair(wih_a1 + (0 * 64 + lane) * 64, wt[0], wt[1]);
    load_row_pair(wih_a1 + (1 * 64 + lane) * 64, wt[2], wt[3]);
    PIN16(wt[0]); PIN16(wt[1]); PIN16(wt[2]); PIN16(wt[3]);
  } else if (wave == 5) {  // a1 proj gates 2,3
    load_row_pair(wih_a1 + (2 * 64 + lane) * 64, wt[0], wt[1]);
    load_row_pair(wih_a1 + (3 * 64 + lane) * 64, wt[2], wt[3]);
    PIN16(wt[0]); PIN16(wt[1]); PIN16(wt[2]); PIN16(wt[3]);
  } else if (wave == 6) {  // a2 proj gates 0,1
    load_row_pair(wih_a2 + (0 * 64 + lane) * 64, wt[0], wt[1]);
    load_row_pair(wih_a2 + (1 * 64 + lane) * 64, wt[2], wt[3]);
    PIN16(wt[0]); PIN16(wt[1]); PIN16(wt[2]); PIN16(wt[3]);
  } else {                 // a2 proj gates 2,3
    load_row_pair(wih_a2 + (2 * 64 + lane) * 64, wt[0], wt[1]);
    load_row_pair(wih_a2 + (3 * 64 + lane) * 64, wt[2], wt[3]);
    PIN16(wt[0]); PIN16(wt[1]); PIN16(wt[2]); PIN16(wt[3]);
  }
  __syncthreads();

  float c = 0.f;
  float h0b = 0.f, c0b = 0.f, h1b = 0.f, c1b = 0.f, h2b = 0.f, c2b = 0.f;

  const int NE = TT / CH + 5;
  for (int e = 0; e < NE; ++e) {
    if (wave == 0) {  // a0 rec, window e
      const int t0 = e * CH;
      if (t0 < TT) {
        __builtin_amdgcn_s_setprio(1);
        for (int s = 0; s < CH; ++s) {
          const int t = t0 + s;
          const float xv = xs[t];
          float p[4];
          mfma_matvec_(bfr, &hh[0][(t + NS - 1) & (NS - 1)][0], lane, p);
          float p0 = __builtin_fmaf(wi0_[0], xv, p[0] + bias[0]);
          float p1 = __builtin_fmaf(wi0_[1], xv, p[1] + bias[1]);
          float p2 = __builtin_fmaf(wi0_[2], xv, p[2] + bias[2]);
          float p3 = __builtin_fmaf(wi0_[3], xv, p[3] + bias[3]);
          float gi = sig_(p0), gf = sig_(p1), gg = tanh_(p2), go = sig_(p3);
          c = __builtin_fmaf(gf, c, gi * gg);
          hh[0][t & (NS - 1)][lane] = (_Float16)(go * tanh_(c));
        }
        __builtin_amdgcn_s_setprio(0);
      }
    } else if (wave == 1) {  // a1 rec, window e-2
      const int t0 = (e - 2) * CH;
      if (t0 >= 0 && t0 < TT) {
        __builtin_amdgcn_s_setprio(1);
        for (int s = 0; s < CH; ++s) {
          const int t = t0 + s;
          float4 pr = *reinterpret_cast<const float4*>(&pj[0][t & (NS - 1)][lane * 4]);
          float p[4];
          mfma_matvec_(bfr, &hh[1][(t + NS - 1) & (NS - 1)][0], lane, p);
          float p0 = p[0] + bias[0] + pr.x;
          float p1 = p[1] + bias[1] + pr.y;
          float p2 = p[2] + bias[2] + pr.z;
          float p3 = p[3] + bias[3] + pr.w;
          float gi = sig_(p0), gf = sig_(p1), gg = tanh_(p2), go = sig_(p3);
          c = __builtin_fmaf(gf, c, gi * gg);
          hh[1][t & (NS - 1)][lane] = (_Float16)(go * tanh_(c));
        }
        __builtin_amdgcn_s_setprio(0);
      }
    } else if (wave == 2) {  // a2 rec, window e-4
      const int t0 = (e - 4) * CH;
      if (t0 >= 0 && t0 < TT) {
        __builtin_amdgcn_s_setprio(1);
        for (int s = 0; s < CH; ++s) {
          const int t = t0 + s;
          float4 pr = *reinterpret_cast<const float4*>(&pj[1][t & (NS - 1)][lane * 4]);
          float p[4];
          mfma_matvec_(bfr, &hh[2][(t + NS - 1) & (NS - 1)][0], lane, p);
          float p0 = p[0] + bias[0] + pr.x;
          float p1 = p[1] + bias[1] + pr.y;
          float p2 = p[2] + bias[2] + pr.z;
          float p3 = p[3] + bias[3] + pr.w;
          float gi = sig_(p0), gf = sig_(p1), gg = tanh_(p2), go = sig_(p3);
          c = __builtin_fmaf(gf, c, gi * gg);
          hh[2][t & (NS - 1)][lane] = (_Float16)(go * tanh_(c));
        }
        __builtin_amdgcn_s_setprio(0);
      }
    } else if (wave == 3) {  // b-chain, window e-5
      const int t0 = (e - 5) * CH;
      if (t0 >= 0 && t0 < TT) {
        for (int s = 0; s < CH; ++s) {
          const int t = t0 + s;
          v2h hv[32];
          load_h64(&hh[2][t & (NS - 1)][0], hv);
          float pga = bias[0], pgb = 0.f;
#pragma unroll
          for (int j = 0; j < 16; ++j) {
            FDOT2(pga, wt[0][j], hv[j]);
            FDOT2(pgb, wt[1][j], hv[16 + j]);
          }
          float pg = pga + pgb;
          float p_i = qb_<0>(pg), p_f = qb_<1>(pg), p_g = qb_<2>(pg), p_o = qb_<3>(pg);
          float i0 = sig_(__builtin_fmaf(whb0[0], h0b, p_i));
          float f0 = sig_(__builtin_fmaf(whb0[1], h0b, p_f));
          float g0 = tanh_(__builtin_fmaf(whb0[2], h0b, p_g));
          float o0 = sig_(__builtin_fmaf(whb0[3], h0b, p_o));
          c0b = __builtin_fmaf(f0, c0b, i0 * g0);
          h0b = o0 * tanh_(c0b);
          float i1 = sig_(bb1[0] + __builtin_fmaf(wi1b[0], h0b, wh1b[0] * h1b));
          float f1 = sig_(bb1[1] + __builtin_fmaf(wi1b[1], h0b, wh1b[1] * h1b));
          float g1 = tanh_(bb1[2] + __builtin_fmaf(wi1b[2], h0b, wh1b[2] * h1b));
          float o1 = sig_(bb1[3] + __builtin_fmaf(wi1b[3], h0b, wh1b[3] * h1b));
          c1b = __builtin_fmaf(f1, c1b, i1 * g1);
          h1b = o1 * tanh_(c1b);
          float i2 = sig_(bb2[0] + __builtin_fmaf(wi2b[0], h1b, wh2b[0] * h2b));
          float f2 = sig_(bb2[1] + __builtin_fmaf(wi2b[1], h1b, wh2b[1] * h2b));
          float g2 = tanh_(bb2[2] + __builtin_fmaf(wi2b[2], h1b, wh2b[2] * h2b));
          float o2 = sig_(bb2[3] + __builtin_fmaf(wi2b[3], h1b, wh2b[3] * h2b));
          c2b = __builtin_fmaf(f2, c2b, i2 * g2);
          h2b = o2 * tanh_(c2b);
          if (lane == 0) out[(size_t)b * TT + t] = h2b;
        }
      }
    } else if (wave == 4) {  // a1 proj g01, window e-1
      const int t0 = (e - 1) * CH;
      if (t0 >= 0 && t0 < TT) {
        for (int s = 0; s < CH; ++s) {
          const int t = t0 + s;
          v2h hv[32];
          load_h64(&hh[0][t & (NS - 1)][0], hv);
          float p0, p1;
          dot2g_(wt[0], wt[1], wt[2], wt[3], hv, p0, p1);
          *reinterpret_cast<float2*>(&pj[0][t & (NS - 1)][lane * 4]) = float2{p0, p1};
        }
      }
    } else if (wave == 5) {  // a1 proj g23, window e-1
      const int t0 = (e - 1) * CH;
      if (t0 >= 0 && t0 < TT) {
        for (int s = 0; s < CH; ++s) {
          const int t = t0 + s;
          v2h hv[32];
          load_h64(&hh[0][t & (NS - 1)][0], hv);
          float p2, p3;
          dot2g_(wt[0], wt[1], wt[2], wt[3], hv, p2, p3);
          *reinterpret_cast<float2*>(&pj[0][t & (NS - 1)][lane * 4 + 2]) = float2{p2, p3};
        }
      }
    } else if (wave == 6) {  // a2 proj g01, window e-3
      const int t0 = (e - 3) * CH;
      if (t0 >= 0 && t0 < TT) {
        for (int s = 0; s < CH; ++s) {
          const int t = t0 + s;
          v2h hv[32];
          load_h64(&hh[1][t & (NS - 1)][0], hv);
          float p0, p1;
          dot2g_(wt[0], wt[1], wt[2], wt[3], hv, p0, p1);
          *reinterpret_cast<float2*>(&pj[1][t & (NS - 1)][lane * 4]) = float2{p0, p1};
        }
      }
    } else {                 // a2 proj g23, window e-3
      const int t0 = (e - 3) * CH;
      if (t0 >= 0 && t0 < TT) {
        for (int s = 0; s < CH; ++s) {
          const int t = t0 + s;
          v2h hv[32];
          load_h64(&hh[1][t & (NS - 1)][0], hv);
          float p2, p3;
          dot2g_(wt[0], wt[1], wt[2], wt[3], hv, p2, p3);
          *reinterpret_cast<float2*>(&pj[1][t & (NS - 1)][lane * 4 + 2]) = float2{p2, p3};
        }
      }
    }
    ldsbar_();
  }
}

extern "C" void kernel_launch(void* const* d_in, const int* in_sizes, int n_in,
                              void* d_out, int out_size, void* d_ws, size_t ws_size,
                              hipStream_t stream) {
  const float* x      = (const float*)d_in[0];
  const float* wih_a0 = (const float*)d_in[1];
  const float* whh_a0 = (const float*)d_in[2];
  const float* bih_a0 = (const float*)d_in[3];
  const float* bhh_a0 = (const float*)d_in[4];
  const float* wih_a1 = (const float*)d_in[5];
  const float* whh_a1 = (const float*)d_in[6];
  const float* bih_a1 = (const float*)d_in[7];
  const float* bhh_a1 = (const float*)d_in[8];
  const float* wih_a2 = (const float*)d_in[9];
  const float* whh_a2 = (const float*)d_in[10];
  const float* bih_a2 = (const float*)d_in[11];
  const float* bhh_a2 = (const float*)d_in[12];
  const float* wih_b0 = (const float*)d_in[13];
  const float* whh_b0 = (const float*)d_in[14];
  const float* bih_b0 = (const float*)d_in[15];
  const float* bhh_b0 = (const float*)d_in[16];
  const float* wih_b1 = (const float*)d_in[17];
  const float* whh_b1 = (const float*)d_in[18];
  const float* bih_b1 = (const float*)d_in[19];
  const float* bhh_b1 = (const float*)d_in[20];
  const float* wih_b2 = (const float*)d_in[21];
  const float* whh_b2 = (const float*)d_in[22];
  const float* bih_b2 = (const float*)d_in[23];
  const float* bhh_b2 = (const float*)d_in[24];
  float* out = (float*)d_out;

  lstm_pipe_k<<<BB, 512, 0, stream>>>(
      x,
      wih_a0, whh_a0, bih_a0, bhh_a0,
      wih_a1, whh_a1, bih_a1, bhh_a1,
      wih_a2, whh_a2, bih_a2, bhh_a2,
      wih_b0, whh_b0, bih_b0, bhh_b0,
      wih_b1, whh_b1, bih_b1, bhh_b1,
      wih_b2, whh_b2, bih_b2, bhh_b2,
      out);
}

// Round 7
// 570.636 us; speedup vs baseline: 1.0231x; 1.0231x over previous
//
#include <hip/hip_runtime.h>

// AttackLSTM R22 — MFMA rec matvec, GROUPED accumulation (fix R21 spill).
// R21 post-mortem: absmax=0 PROVES the MFMA formulation (B-frag layout,
// A kmap, hid(lane)=lane) is correct. But acc[16] (64 regs) + bfr (128 AGPR)
// = 192 AGPR demand > 128 -> scratch spill (WRITE_SIZE 22.6MB), dur 519.
// R22: tile group g == gate g (tiles 4g..4g+3 = outputs 64g..64g+63).
// Per group: 8 MFMAs -> extract p[g] (3 cndmask) -> sched_barrier(0) -> next.
// Max 4 acc tiles live (16 arch VGPRs); sched_barrier stops the scheduler
// from hoisting all 32 MFMAs and recreating the 16-tile liveness.
// Rec: ~150cy VALU issue + 4 b64 LDS/step (was 8 b128). Per-epoch LDS
// ~4400cy vs ~10800 (R20, near-saturated). Everything else verbatim R21.
// Verify: WRITE_SIZE ~512KB. If clean but dur>=330us: rec wasn't binding.
// Stage schedule (epoch e): w0 a0rec@e | w4,5 a1proj@e-1 | w1 a1rec@e-2 |
// w6,7 a2proj@e-3 | w2 a2rec@e-4 | w3 b-chain@e-5.  CH=8, NS=16.

#define BB 256
#define TT 512
#define CH 8
#define NS 16  // ring slots = 2*CH

typedef _Float16 v2h __attribute__((ext_vector_type(2)));
typedef _Float16 v8h __attribute__((ext_vector_type(8)));
typedef float v4f __attribute__((ext_vector_type(4)));

__device__ __forceinline__ float sig_(float x) {
  return __builtin_amdgcn_rcpf(1.f + __builtin_amdgcn_exp2f(-1.44269504f * x));
}
__device__ __forceinline__ float tanh_(float x) {
  return __builtin_fmaf(2.f, __builtin_amdgcn_rcpf(1.f + __builtin_amdgcn_exp2f(-2.88539008f * x)), -1.f);
}

template <int K>
__device__ __forceinline__ float qb_(float v) {
  return __int_as_float(__builtin_amdgcn_update_dpp(
      0, __float_as_int(v), (K | (K << 2) | (K << 4) | (K << 6)), 0xF, 0xF, true));
}

__device__ __forceinline__ void ldsbar_() {
  asm volatile("s_waitcnt lgkmcnt(0)\n\ts_barrier" ::: "memory");
}

#if __has_builtin(__builtin_amdgcn_fdot2)
#define FDOT2(acc, a, b) (acc) = __builtin_amdgcn_fdot2((a), (b), (acc), false)
#else
#define FDOT2(acc, a, b) \
  (acc) = __builtin_fmaf((float)(a)[0], (float)(b)[0], \
          __builtin_fmaf((float)(a)[1], (float)(b)[1], (acc)))
#endif
#define KEEPP(a) asm volatile("" : "+v"(a))
#define PIN16(w)                                                            \
  do {                                                                      \
    _Pragma("unroll") for (int _i = 0; _i < 16; ++_i) KEEPP((w)[_i]);       \
  } while (0)

__device__ __forceinline__ v2h bc2h_(int v) { return __builtin_bit_cast(v2h, v); }

// 64 halfs from LDS as 32 v2h via int4 reads (8x ds_read_b128).
__device__ __forceinline__ void load_h64(const _Float16* p, v2h hv[32]) {
  const int4* hp = reinterpret_cast<const int4*>(p);
#pragma unroll
  for (int i = 0; i < 8; ++i) {
    int4 blk = hp[i];
    hv[4 * i + 0] = bc2h_(blk.x);
    hv[4 * i + 1] = bc2h_(blk.y);
    hv[4 * i + 2] = bc2h_(blk.z);
    hv[4 * i + 3] = bc2h_(blk.w);
  }
}

// fp32 row of 64 -> two 16-v2h halves (k 0..31 -> lo, k 32..63 -> hi).
__device__ __forceinline__ void load_row_pair(const float* src, v2h lo[16], v2h hi[16]) {
  const float4* p = reinterpret_cast<const float4*>(src);
#pragma unroll
  for (int i = 0; i < 8; ++i) {
    float4 v = p[i];
    lo[2 * i]     = v2h{(_Float16)v.x, (_Float16)v.y};
    lo[2 * i + 1] = v2h{(_Float16)v.z, (_Float16)v.w};
  }
#pragma unroll
  for (int i = 0; i < 8; ++i) {
    float4 v = p[8 + i];
    hi[2 * i]     = v2h{(_Float16)v.x, (_Float16)v.y};
    hi[2 * i + 1] = v2h{(_Float16)v.z, (_Float16)v.w};
  }
}

// B-fragment for tile t, K-chunk kc of W[256x64] (row-major f32).
// Lane l holds B[k, col=l&15] = W[16t+(l&15)][32kc + kmap(j)],
// kmap: j=0..3 -> 4*(l>>4)+j ; j=4..7 -> 16+4*(l>>4)+(j-4).
__device__ __forceinline__ v8h ldbfrag_(const float* W, int t, int kc, int lane) {
  const int row = 16 * t + (lane & 15);
  const float* p = W + row * 64 + 32 * kc + 4 * (lane >> 4);
  float4 fa = *reinterpret_cast<const float4*>(p);
  float4 fb = *reinterpret_cast<const float4*>(p + 16);
  return v8h{(_Float16)fa.x, (_Float16)fa.y, (_Float16)fa.z, (_Float16)fa.w,
             (_Float16)fb.x, (_Float16)fb.y, (_Float16)fb.z, (_Float16)fb.w};
}

// p[256] = W*h via 32 MFMAs in 4 groups (group g = gate g, tiles 4g..4g+3).
// Only 4 acc tiles live at a time; sched_barrier(0) pins group boundaries
// so the scheduler can't hoist all MFMAs and blow the register budget (R21).
__device__ __forceinline__ void mfma_matvec_(const v8h bfr[16][2],
                                             const _Float16* hprev, int lane,
                                             float p[4]) {
  const char* hp = reinterpret_cast<const char*>(hprev);
  const int off = 8 * (lane >> 4);
  int2 r00 = *reinterpret_cast<const int2*>(hp + off);        // kc0, k 0..15 blk
  int2 r01 = *reinterpret_cast<const int2*>(hp + off + 32);   // kc0, k 16..31 blk
  int2 r10 = *reinterpret_cast<const int2*>(hp + off + 64);   // kc1
  int2 r11 = *reinterpret_cast<const int2*>(hp + off + 96);
  v8h A0 = __builtin_bit_cast(v8h, int4{r00.x, r00.y, r01.x, r01.y});
  v8h A1 = __builtin_bit_cast(v8h, int4{r10.x, r10.y, r11.x, r11.y});
  const v4f z = {0.f, 0.f, 0.f, 0.f};
  const int q = lane >> 4;
  const bool s0 = q & 1, s1 = q & 2;
#pragma unroll
  for (int g = 0; g < 4; ++g) {
    v4f a0 = __builtin_amdgcn_mfma_f32_16x16x32_f16(A0, bfr[4 * g + 0][0], z, 0, 0, 0);
    a0 = __builtin_amdgcn_mfma_f32_16x16x32_f16(A1, bfr[4 * g + 0][1], a0, 0, 0, 0);
    v4f a1 = __builtin_amdgcn_mfma_f32_16x16x32_f16(A0, bfr[4 * g + 1][0], z, 0, 0, 0);
    a1 = __builtin_amdgcn_mfma_f32_16x16x32_f16(A1, bfr[4 * g + 1][1], a1, 0, 0, 0);
    v4f a2 = __builtin_amdgcn_mfma_f32_16x16x32_f16(A0, bfr[4 * g + 2][0], z, 0, 0, 0);
    a2 = __builtin_amdgcn_mfma_f32_16x16x32_f16(A1, bfr[4 * g + 2][1], a2, 0, 0, 0);
    v4f a3 = __builtin_amdgcn_mfma_f32_16x16x32_f16(A0, bfr[4 * g + 3][0], z, 0, 0, 0);
    a3 = __builtin_amdgcn_mfma_f32_16x16x32_f16(A1, bfr[4 * g + 3][1], a3, 0, 0, 0);
    float v01 = s0 ? a1[0] : a0[0];
    float v23 = s0 ? a3[0] : a2[0];
    p[g] = s1 ? v23 : v01;
    __builtin_amdgcn_sched_barrier(0);
  }
}

// 2-gate proj dot over full k (gate A: wa_lo/wa_hi, gate B: wb_lo/wb_hi).
__device__ __forceinline__ void dot2g_(const v2h* wa_lo, const v2h* wa_hi,
                                       const v2h* wb_lo, const v2h* wb_hi,
                                       const v2h hv[32], float& p0, float& p1) {
  float a0 = 0.f, a1 = 0.f, b0 = 0.f, b1 = 0.f;
#pragma unroll
  for (int j = 0; j < 16; j += 2) {
    FDOT2(a0, wa_lo[j], hv[j]);          FDOT2(b0, wa_lo[j + 1], hv[j + 1]);
    FDOT2(a0, wa_hi[j], hv[16 + j]);     FDOT2(b0, wa_hi[j + 1], hv[17 + j]);
    FDOT2(a1, wb_lo[j], hv[j]);          FDOT2(b1, wb_lo[j + 1], hv[j + 1]);
    FDOT2(a1, wb_hi[j], hv[16 + j]);     FDOT2(b1, wb_hi[j + 1], hv[17 + j]);
  }
  p0 = a0 + b0; p1 = a1 + b1;
}

__global__ __attribute__((amdgpu_flat_work_group_size(512, 512),
                          amdgpu_waves_per_eu(2, 2)))
void lstm_pipe_k(
    const float* __restrict__ x,
    const float* __restrict__ wih_a0, const float* __restrict__ whh_a0,
    const float* __restrict__ bih_a0, const float* __restrict__ bhh_a0,
    const float* __restrict__ wih_a1, const float* __restrict__ whh_a1,
    const float* __restrict__ bih_a1, const float* __restrict__ bhh_a1,
    const float* __restrict__ wih_a2, const float* __restrict__ whh_a2,
    const float* __restrict__ bih_a2, const float* __restrict__ bhh_a2,
    const float* __restrict__ wih_b0, const float* __restrict__ whh_b0,
    const float* __restrict__ bih_b0, const float* __restrict__ bhh_b0,
    const float* __restrict__ wih_b1, const float* __restrict__ whh_b1,
    const float* __restrict__ bih_b1, const float* __restrict__ bhh_b1,
    const float* __restrict__ wih_b2, const float* __restrict__ whh_b2,
    const float* __restrict__ bih_b2, const float* __restrict__ bhh_b2,
    float* __restrict__ out)  // [B,T]
{
  const int b = blockIdx.x;
  const int tid = threadIdx.x;
  const int wave = tid >> 6;
  const int lane = tid & 63;

  __shared__ __align__(16) _Float16 hh[3][NS][64];  // h rings
  __shared__ __align__(16) float pj[2][NS][256];    // proj rings [hid][gate]
  __shared__ float xs[TT];

  for (int i = tid; i < TT; i += 512) xs[i] = x[(size_t)b * TT + i];
  for (int i = tid; i < 3 * NS * 64 / 2; i += 512) reinterpret_cast<int*>(hh)[i] = 0;

  v8h bfr[16][2];   // rec waves: MFMA B-fragments (AGPR-resident)
  v2h wt[4][16];    // proj/b waves: register weights (arch VGPR)
  float bias[4] = {0.f, 0.f, 0.f, 0.f};
  float wi0_[4] = {0.f, 0.f, 0.f, 0.f};
  float whb0[4] = {}, wi1b[4] = {}, wh1b[4] = {}, bb1[4] = {},
        wi2b[4] = {}, wh2b[4] = {}, bb2[4] = {};

  if (wave == 0) {  // a0 recurrence
#pragma unroll
    for (int t = 0; t < 16; ++t) {
      bfr[t][0] = ldbfrag_(whh_a0, t, 0, lane);
      bfr[t][1] = ldbfrag_(whh_a0, t, 1, lane);
    }
#pragma unroll
    for (int q = 0; q < 4; ++q) {
      const int row = q * 64 + lane;
      bias[q] = bih_a0[row] + bhh_a0[row];
      wi0_[q] = wih_a0[row];
    }
  } else if (wave == 1) {  // a1 recurrence
#pragma unroll
    for (int t = 0; t < 16; ++t) {
      bfr[t][0] = ldbfrag_(whh_a1, t, 0, lane);
      bfr[t][1] = ldbfrag_(whh_a1, t, 1, lane);
    }
#pragma unroll
    for (int q = 0; q < 4; ++q) bias[q] = bih_a1[q * 64 + lane] + bhh_a1[q * 64 + lane];
  } else if (wave == 2) {  // a2 recurrence
#pragma unroll
    for (int t = 0; t < 16; ++t) {
      bfr[t][0] = ldbfrag_(whh_a2, t, 0, lane);
      bfr[t][1] = ldbfrag_(whh_a2, t, 1, lane);
    }
#pragma unroll
    for (int q = 0; q < 4; ++q) bias[q] = bih_a2[q * 64 + lane] + bhh_a2[q * 64 + lane];
  } else if (wave == 3) {  // b-chain: one row of wih_b0 in wt[0](lo)/wt[1](hi)
    const int q = lane & 3;
    load_row_pair(wih_b0 + q * 64, wt[0], wt[1]);
    bias[0] = bih_b0[q] + bhh_b0[q];
#pragma unroll
    for (int k = 0; k < 4; ++k) {
      whb0[k] = whh_b0[k];
      wi1b[k] = wih_b1[k]; wh1b[k] = whh_b1[k]; bb1[k] = bih_b1[k] + bhh_b1[k];
      wi2b[k] = wih_b2[k]; wh2b[k] = whh_b2[k]; bb2[k] = bih_b2[k] + bhh_b2[k];
    }
    PIN16(wt[0]); PIN16(wt[1]);
  } else if (wave == 4) {  // a1 proj gates 0,1
    load_row_pair(wih_a1 + (0 * 64 + lane) * 64, wt[0], wt[1]);
    load_row_pair(wih_a1 + (1 * 64 + lane) * 64, wt[2], wt[3]);
    PIN16(wt[0]); PIN16(wt[1]); PIN16(wt[2]); PIN16(wt[3]);
  } else if (wave == 5) {  // a1 proj gates 2,3
    load_row_pair(wih_a1 + (2 * 64 + lane) * 64, wt[0], wt[1]);
    load_row_pair(wih_a1 + (3 * 64 + lane) * 64, wt[2], wt[3]);
    PIN16(wt[0]); PIN16(wt[1]); PIN16(wt[2]); PIN16(wt[3]);
  } else if (wave == 6) {  // a2 proj gates 0,1
    load_row_pair(wih_a2 + (0 * 64 + lane) * 64, wt[0], wt[1]);
    load_row_pair(wih_a2 + (1 * 64 + lane) * 64, wt[2], wt[3]);
    PIN16(wt[0]); PIN16(wt[1]); PIN16(wt[2]); PIN16(wt[3]);
  } else {                 // a2 proj gates 2,3
    load_row_pair(wih_a2 + (2 * 64 + lane) * 64, wt[0], wt[1]);
    load_row_pair(wih_a2 + (3 * 64 + lane) * 64, wt[2], wt[3]);
    PIN16(wt[0]); PIN16(wt[1]); PIN16(wt[2]); PIN16(wt[3]);
  }
  __syncthreads();

  float c = 0.f;
  float h0b = 0.f, c0b = 0.f, h1b = 0.f, c1b = 0.f, h2b = 0.f, c2b = 0.f;

  const int NE = TT / CH + 5;
  for (int e = 0; e < NE; ++e) {
    if (wave == 0) {  // a0 rec, window e
      const int t0 = e * CH;
      if (t0 < TT) {
        __builtin_amdgcn_s_setprio(1);
        for (int s = 0; s < CH; ++s) {
          const int t = t0 + s;
          const float xv = xs[t];
          float p[4];
          mfma_matvec_(bfr, &hh[0][(t + NS - 1) & (NS - 1)][0], lane, p);
          float p0 = __builtin_fmaf(wi0_[0], xv, p[0] + bias[0]);
          float p1 = __builtin_fmaf(wi0_[1], xv, p[1] + bias[1]);
          float p2 = __builtin_fmaf(wi0_[2], xv, p[2] + bias[2]);
          float p3 = __builtin_fmaf(wi0_[3], xv, p[3] + bias[3]);
          float gi = sig_(p0), gf = sig_(p1), gg = tanh_(p2), go = sig_(p3);
          c = __builtin_fmaf(gf, c, gi * gg);
          hh[0][t & (NS - 1)][lane] = (_Float16)(go * tanh_(c));
        }
        __builtin_amdgcn_s_setprio(0);
      }
    } else if (wave == 1) {  // a1 rec, window e-2
      const int t0 = (e - 2) * CH;
      if (t0 >= 0 && t0 < TT) {
        __builtin_amdgcn_s_setprio(1);
        for (int s = 0; s < CH; ++s) {
          const int t = t0 + s;
          float4 pr = *reinterpret_cast<const float4*>(&pj[0][t & (NS - 1)][lane * 4]);
          float p[4];
          mfma_matvec_(bfr, &hh[1][(t + NS - 1) & (NS - 1)][0], lane, p);
          float p0 = p[0] + bias[0] + pr.x;
          float p1 = p[1] + bias[1] + pr.y;
          float p2 = p[2] + bias[2] + pr.z;
          float p3 = p[3] + bias[3] + pr.w;
          float gi = sig_(p0), gf = sig_(p1), gg = tanh_(p2), go = sig_(p3);
          c = __builtin_fmaf(gf, c, gi * gg);
          hh[1][t & (NS - 1)][lane] = (_Float16)(go * tanh_(c));
        }
        __builtin_amdgcn_s_setprio(0);
      }
    } else if (wave == 2) {  // a2 rec, window e-4
      const int t0 = (e - 4) * CH;
      if (t0 >= 0 && t0 < TT) {
        __builtin_amdgcn_s_setprio(1);
        for (int s = 0; s < CH; ++s) {
          const int t = t0 + s;
          float4 pr = *reinterpret_cast<const float4*>(&pj[1][t & (NS - 1)][lane * 4]);
          float p[4];
          mfma_matvec_(bfr, &hh[2][(t + NS - 1) & (NS - 1)][0], lane, p);
          float p0 = p[0] + bias[0] + pr.x;
          float p1 = p[1] + bias[1] + pr.y;
          float p2 = p[2] + bias[2] + pr.z;
          float p3 = p[3] + bias[3] + pr.w;
          float gi = sig_(p0), gf = sig_(p1), gg = tanh_(p2), go = sig_(p3);
          c = __builtin_fmaf(gf, c, gi * gg);
          hh[2][t & (NS - 1)][lane] = (_Float16)(go * tanh_(c));
        }
        __builtin_amdgcn_s_setprio(0);
      }
    } else if (wave == 3) {  // b-chain, window e-5
      const int t0 = (e - 5) * CH;
      if (t0 >= 0 && t0 < TT) {
        for (int s = 0; s < CH; ++s) {
          const int t = t0 + s;
          v2h hv[32];
          load_h64(&hh[2][t & (NS - 1)][0], hv);
          float pga = bias[0], pgb = 0.f;
#pragma unroll
          for (int j = 0; j < 16; ++j) {
            FDOT2(pga, wt[0][j], hv[j]);
            FDOT2(pgb, wt[1][j], hv[16 + j]);
          }
          float pg = pga + pgb;
          float p_i = qb_<0>(pg), p_f = qb_<1>(pg), p_g = qb_<2>(pg), p_o = qb_<3>(pg);
          float i0 = sig_(__builtin_fmaf(whb0[0], h0b, p_i));
          float f0 = sig_(__builtin_fmaf(whb0[1], h0b, p_f));
          float g0 = tanh_(__builtin_fmaf(whb0[2], h0b, p_g));
          float o0 = sig_(__builtin_fmaf(whb0[3], h0b, p_o));
          c0b = __builtin_fmaf(f0, c0b, i0 * g0);
          h0b = o0 * tanh_(c0b);
          float i1 = sig_(bb1[0] + __builtin_fmaf(wi1b[0], h0b, wh1b[0] * h1b));
          float f1 = sig_(bb1[1] + __builtin_fmaf(wi1b[1], h0b, wh1b[1] * h1b));
          float g1 = tanh_(bb1[2] + __builtin_fmaf(wi1b[2], h0b, wh1b[2] * h1b));
          float o1 = sig_(bb1[3] + __builtin_fmaf(wi1b[3], h0b, wh1b[3] * h1b));
          c1b = __builtin_fmaf(f1, c1b, i1 * g1);
          h1b = o1 * tanh_(c1b);
          float i2 = sig_(bb2[0] + __builtin_fmaf(wi2b[0], h1b, wh2b[0] * h2b));
          float f2 = sig_(bb2[1] + __builtin_fmaf(wi2b[1], h1b, wh2b[1] * h2b));
          float g2 = tanh_(bb2[2] + __builtin_fmaf(wi2b[2], h1b, wh2b[2] * h2b));
          float o2 = sig_(bb2[3] + __builtin_fmaf(wi2b[3], h1b, wh2b[3] * h2b));
          c2b = __builtin_fmaf(f2, c2b, i2 * g2);
          h2b = o2 * tanh_(c2b);
          if (lane == 0) out[(size_t)b * TT + t] = h2b;
        }
      }
    } else if (wave == 4) {  // a1 proj g01, window e-1
      const int t0 = (e - 1) * CH;
      if (t0 >= 0 && t0 < TT) {
        for (int s = 0; s < CH; ++s) {
          const int t = t0 + s;
          v2h hv[32];
          load_h64(&hh[0][t & (NS - 1)][0], hv);
          float p0, p1;
          dot2g_(wt[0], wt[1], wt[2], wt[3], hv, p0, p1);
          *reinterpret_cast<float2*>(&pj[0][t & (NS - 1)][lane * 4]) = float2{p0, p1};
        }
      }
    } else if (wave == 5) {  // a1 proj g23, window e-1
      const int t0 = (e - 1) * CH;
      if (t0 >= 0 && t0 < TT) {
        for (int s = 0; s < CH; ++s) {
          const int t = t0 + s;
          v2h hv[32];
          load_h64(&hh[0][t & (NS - 1)][0], hv);
          float p2, p3;
          dot2g_(wt[0], wt[1], wt[2], wt[3], hv, p2, p3);
          *reinterpret_cast<float2*>(&pj[0][t & (NS - 1)][lane * 4 + 2]) = float2{p2, p3};
        }
      }
    } else if (wave == 6) {  // a2 proj g01, window e-3
      const int t0 = (e - 3) * CH;
      if (t0 >= 0 && t0 < TT) {
        for (int s = 0; s < CH; ++s) {
          const int t = t0 + s;
          v2h hv[32];
          load_h64(&hh[1][t & (NS - 1)][0], hv);
          float p0, p1;
          dot2g_(wt[0], wt[1], wt[2], wt[3], hv, p0, p1);
          *reinterpret_cast<float2*>(&pj[1][t & (NS - 1)][lane * 4]) = float2{p0, p1};
        }
      }
    } else {                 // a2 proj g23, window e-3
      const int t0 = (e - 3) * CH;
      if (t0 >= 0 && t0 < TT) {
        for (int s = 0; s < CH; ++s) {
          const int t = t0 + s;
          v2h hv[32];
          load_h64(&hh[1][t & (NS - 1)][0], hv);
          float p2, p3;
          dot2g_(wt[0], wt[1], wt[2], wt[3], hv, p2, p3);
          *reinterpret_cast<float2*>(&pj[1][t & (NS - 1)][lane * 4 + 2]) = float2{p2, p3};
        }
      }
    }
    ldsbar_();
  }
}

extern "C" void kernel_launch(void* const* d_in, const int* in_sizes, int n_in,
                              void* d_out, int out_size, void* d_ws, size_t ws_size,
                              hipStream_t stream) {
  const float* x      = (const float*)d_in[0];
  const float* wih_a0 = (const float*)d_in[1];
  const float* whh_a0 = (const float*)d_in[2];
  const float* bih_a0 = (const float*)d_in[3];
  const float* bhh_a0 = (const float*)d_in[4];
  const float* wih_a1 = (const float*)d_in[5];
  const float* whh_a1 = (const float*)d_in[6];
  const float* bih_a1 = (const float*)d_in[7];
  const float* bhh_a1 = (const float*)d_in[8];
  const float* wih_a2 = (const float*)d_in[9];
  const float* whh_a2 = (const float*)d_in[10];
  const float* bih_a2 = (const float*)d_in[11];
  const float* bhh_a2 = (const float*)d_in[12];
  const float* wih_b0 = (const float*)d_in[13];
  const float* whh_b0 = (const float*)d_in[14];
  const float* bih_b0 = (const float*)d_in[15];
  const float* bhh_b0 = (const float*)d_in[16];
  const float* wih_b1 = (const float*)d_in[17];
  const float* whh_b1 = (const float*)d_in[18];
  const float* bih_b1 = (const float*)d_in[19];
  const float* bhh_b1 = (const float*)d_in[20];
  const float* wih_b2 = (const float*)d_in[21];
  const float* whh_b2 = (const float*)d_in[22];
  const float* bih_b2 = (const float*)d_in[23];
  const float* bhh_b2 = (const float*)d_in[24];
  float* out = (float*)d_out;

  lstm_pipe_k<<<BB, 512, 0, stream>>>(
      x,
      wih_a0, whh_a0, bih_a0, bhh_a0,
      wih_a1, whh_a1, bih_a1, bhh_a1,
      wih_a2, whh_a2, bih_a2, bhh_a2,
      wih_b0, whh_b0, bih_b0, bhh_b0,
      wih_b1, whh_b1, bih_b1, bhh_b1,
      wih_b2, whh_b2, bih_b2, bhh_b2,
      out);
}

// Round 8
// 401.017 us; speedup vs baseline: 1.4558x; 1.4230x over previous
//
#include <hip/hip_runtime.h>

// AttackLSTM R23 — self-timed pipeline: LDS progress counters replace s_barrier.
// R22 post-mortem: MFMA path 507us > fdot2 354us — engine is not the lever.
// Invariant across R16-R22: ~1535cy/step = serial chain + 8-wave barrier
// convoy (epoch = max(stage) + rendezvous spread, x69). R23 removes the
// convoy: prog[8] epoch counters in LDS; producer publishes prog[w]=k+1
// (lgkmcnt(0) then release ds_write -> DS in-order => flag-visible implies
// data-visible); consumers acquire-spin only on DIRECT producers. Ring
// back-pressure: NS=16 = 2 windows -> producer waits consumer prog>=k-1.
// Wait graph over k is a DAG with slack>=1 => deadlock-free. Waves decouple;
// total ~ slowest stage serial + drain. Compute = verbatim R20 (354us,
// fdot2 + half-LDS-streamed rec weights, VGPR 116, no spill) to isolate
// the sync change. Edges: w0(a0)->w4,w5(a1proj)->w1(a1rec)->w6,w7(a2proj)
// ->w2(a2rec)->w3(b-chain). CH=8, NS=16, 64 windows.

#define BB 256
#define TT 512
#define CH 8
#define NS 16  // ring slots = 2*CH
#define NW (TT / CH)

typedef _Float16 v2h __attribute__((ext_vector_type(2)));

__device__ __forceinline__ float sig_(float x) {
  return __builtin_amdgcn_rcpf(1.f + __builtin_amdgcn_exp2f(-1.44269504f * x));
}
__device__ __forceinline__ float tanh_(float x) {
  return __builtin_fmaf(2.f, __builtin_amdgcn_rcpf(1.f + __builtin_amdgcn_exp2f(-2.88539008f * x)), -1.f);
}

template <int K>
__device__ __forceinline__ float qb_(float v) {
  return __int_as_float(__builtin_amdgcn_update_dpp(
      0, __float_as_int(v), (K | (K << 2) | (K << 4) | (K << 6)), 0xF, 0xF, true));
}

#if __has_builtin(__builtin_amdgcn_fdot2)
#define FDOT2(acc, a, b) (acc) = __builtin_amdgcn_fdot2((a), (b), (acc), false)
#else
#define FDOT2(acc, a, b) \
  (acc) = __builtin_fmaf((float)(a)[0], (float)(b)[0], \
          __builtin_fmaf((float)(a)[1], (float)(b)[1], (acc)))
#endif
#define KEEPP(a) asm volatile("" : "+v"(a))
#define PIN16(w)                                                            \
  do {                                                                      \
    _Pragma("unroll") for (int _i = 0; _i < 16; ++_i) KEEPP((w)[_i]);       \
  } while (0)

// Spin until prog[i] >= v (acquire). All lanes poll same addr (broadcast).
#define WAITP(i, v)                                                           \
  while (__hip_atomic_load(&prog[i], __ATOMIC_ACQUIRE,                        \
                           __HIP_MEMORY_SCOPE_WORKGROUP) < (v)) {}
// Publish prog[i] = v after all this wave's data ds_writes retired.
#define POSTP(i, v)                                                           \
  do {                                                                        \
    asm volatile("s_waitcnt lgkmcnt(0)" ::: "memory");                        \
    if (lane == 0)                                                            \
      __hip_atomic_store(&prog[i], (v), __ATOMIC_RELEASE,                     \
                         __HIP_MEMORY_SCOPE_WORKGROUP);                       \
  } while (0)

__device__ __forceinline__ v2h bc2h_(int v) { return __builtin_bit_cast(v2h, v); }
__device__ __forceinline__ int pk2_(float x, float y) {
  return __builtin_bit_cast(int, v2h{(_Float16)x, (_Float16)y});
}

// 64 halfs from LDS as 32 v2h via int4 reads (8x ds_read_b128).
__device__ __forceinline__ void load_h64(const _Float16* p, v2h hv[32]) {
  const int4* hp = reinterpret_cast<const int4*>(p);
#pragma unroll
  for (int i = 0; i < 8; ++i) {
    int4 blk = hp[i];
    hv[4 * i + 0] = bc2h_(blk.x);
    hv[4 * i + 1] = bc2h_(blk.y);
    hv[4 * i + 2] = bc2h_(blk.z);
    hv[4 * i + 3] = bc2h_(blk.w);
  }
}

// fp32 row of 64 -> two 16-v2h halves (k 0..31 -> lo, k 32..63 -> hi).
__device__ __forceinline__ void load_row_pair(const float* src, v2h lo[16], v2h hi[16]) {
  const float4* p = reinterpret_cast<const float4*>(src);
#pragma unroll
  for (int i = 0; i < 8; ++i) {
    float4 v = p[i];
    lo[2 * i]     = v2h{(_Float16)v.x, (_Float16)v.y};
    lo[2 * i + 1] = v2h{(_Float16)v.z, (_Float16)v.w};
  }
#pragma unroll
  for (int i = 0; i < 8; ++i) {
    float4 v = p[8 + i];
    hi[2 * i]     = v2h{(_Float16)v.x, (_Float16)v.y};
    hi[2 * i + 1] = v2h{(_Float16)v.z, (_Float16)v.w};
  }
}

// Rec-wave weight preload: K 0..31 of rows q*64+lane into arch regs wt[q],
// K 32..63 converted and written to the LDS weight mirror (80B row pitch).
__device__ __forceinline__ void load_rec_w(const float* W, int lane,
                                           v2h wt[4][16], unsigned char* wl) {
#pragma unroll
  for (int q = 0; q < 4; ++q) {
    const int row = q * 64 + lane;
    const float4* p = reinterpret_cast<const float4*>(W + row * 64);
#pragma unroll
    for (int i = 0; i < 8; ++i) {
      float4 v = p[i];
      wt[q][2 * i]     = v2h{(_Float16)v.x, (_Float16)v.y};
      wt[q][2 * i + 1] = v2h{(_Float16)v.z, (_Float16)v.w};
    }
#pragma unroll
    for (int i = 0; i < 4; ++i) {
      float4 va = p[8 + 2 * i], vb = p[9 + 2 * i];
      int4 blk;
      blk.x = pk2_(va.x, va.y); blk.y = pk2_(va.z, va.w);
      blk.z = pk2_(vb.x, vb.y); blk.w = pk2_(vb.z, vb.w);
      *reinterpret_cast<int4*>(wl + row * 80 + i * 16) = blk;
    }
  }
}

// Full 4-gate dot: arch half (wt, k 0..31) + LDS-streamed half (k 32..63).
__device__ __forceinline__ void dot4full_(const v2h wt[4][16],
                                          const unsigned char* wl, int lane,
                                          const v2h hv[32],
                                          float& p0, float& p1, float& p2, float& p3) {
  float a0 = p0, a1 = p1, a2 = p2, a3 = p3;
  float b0 = 0.f, b1 = 0.f, b2 = 0.f, b3 = 0.f;
#pragma unroll
  for (int j = 0; j < 16; j += 2) {
    FDOT2(a0, wt[0][j], hv[j]);         FDOT2(a1, wt[1][j], hv[j]);
    FDOT2(a2, wt[2][j], hv[j]);         FDOT2(a3, wt[3][j], hv[j]);
    FDOT2(b0, wt[0][j + 1], hv[j + 1]); FDOT2(b1, wt[1][j + 1], hv[j + 1]);
    FDOT2(b2, wt[2][j + 1], hv[j + 1]); FDOT2(b3, wt[3][j + 1], hv[j + 1]);
  }
  const int rb0 = lane * 80, rb1 = (64 + lane) * 80,
            rb2 = (128 + lane) * 80, rb3 = (192 + lane) * 80;
#pragma unroll
  for (int jb = 0; jb < 4; ++jb) {
    int4 w0 = *reinterpret_cast<const int4*>(wl + rb0 + jb * 16);
    int4 w1 = *reinterpret_cast<const int4*>(wl + rb1 + jb * 16);
    int4 w2 = *reinterpret_cast<const int4*>(wl + rb2 + jb * 16);
    int4 w3 = *reinterpret_cast<const int4*>(wl + rb3 + jb * 16);
    const int h0 = 16 + jb * 4;
    FDOT2(a0, bc2h_(w0.x), hv[h0 + 0]); FDOT2(b0, bc2h_(w0.y), hv[h0 + 1]);
    FDOT2(a0, bc2h_(w0.z), hv[h0 + 2]); FDOT2(b0, bc2h_(w0.w), hv[h0 + 3]);
    FDOT2(a1, bc2h_(w1.x), hv[h0 + 0]); FDOT2(b1, bc2h_(w1.y), hv[h0 + 1]);
    FDOT2(a1, bc2h_(w1.z), hv[h0 + 2]); FDOT2(b1, bc2h_(w1.w), hv[h0 + 3]);
    FDOT2(a2, bc2h_(w2.x), hv[h0 + 0]); FDOT2(b2, bc2h_(w2.y), hv[h0 + 1]);
    FDOT2(a2, bc2h_(w2.z), hv[h0 + 2]); FDOT2(b2, bc2h_(w2.w), hv[h0 + 3]);
    FDOT2(a3, bc2h_(w3.x), hv[h0 + 0]); FDOT2(b3, bc2h_(w3.y), hv[h0 + 1]);
    FDOT2(a3, bc2h_(w3.z), hv[h0 + 2]); FDOT2(b3, bc2h_(w3.w), hv[h0 + 3]);
  }
  p0 = a0 + b0; p1 = a1 + b1; p2 = a2 + b2; p3 = a3 + b3;
}

// 2-gate proj dot over full k (gate A: wa_lo/wa_hi, gate B: wb_lo/wb_hi).
__device__ __forceinline__ void dot2g_(const v2h* wa_lo, const v2h* wa_hi,
                                       const v2h* wb_lo, const v2h* wb_hi,
                                       const v2h hv[32], float& p0, float& p1) {
  float a0 = 0.f, a1 = 0.f, b0 = 0.f, b1 = 0.f;
#pragma unroll
  for (int j = 0; j < 16; j += 2) {
    FDOT2(a0, wa_lo[j], hv[j]);          FDOT2(b0, wa_lo[j + 1], hv[j + 1]);
    FDOT2(a0, wa_hi[j], hv[16 + j]);     FDOT2(b0, wa_hi[j + 1], hv[17 + j]);
    FDOT2(a1, wb_lo[j], hv[j]);          FDOT2(b1, wb_lo[j + 1], hv[j + 1]);
    FDOT2(a1, wb_hi[j], hv[16 + j]);     FDOT2(b1, wb_hi[j + 1], hv[17 + j]);
  }
  p0 = a0 + b0; p1 = a1 + b1;
}

__global__ __attribute__((amdgpu_flat_work_group_size(512, 512),
                          amdgpu_waves_per_eu(2, 2)))
void lstm_pipe_k(
    const float* __restrict__ x,
    const float* __restrict__ wih_a0, const float* __restrict__ whh_a0,
    const float* __restrict__ bih_a0, const float* __restrict__ bhh_a0,
    const float* __restrict__ wih_a1, const float* __restrict__ whh_a1,
    const float* __restrict__ bih_a1, const float* __restrict__ bhh_a1,
    const float* __restrict__ wih_a2, const float* __restrict__ whh_a2,
    const float* __restrict__ bih_a2, const float* __restrict__ bhh_a2,
    const float* __restrict__ wih_b0, const float* __restrict__ whh_b0,
    const float* __restrict__ bih_b0, const float* __restrict__ bhh_b0,
    const float* __restrict__ wih_b1, const float* __restrict__ whh_b1,
    const float* __restrict__ bih_b1, const float* __restrict__ bhh_b1,
    const float* __restrict__ wih_b2, const float* __restrict__ whh_b2,
    const float* __restrict__ bih_b2, const float* __restrict__ bhh_b2,
    float* __restrict__ out)  // [B,T]
{
  const int b = blockIdx.x;
  const int tid = threadIdx.x;
  const int wave = tid >> 6;
  const int lane = tid & 63;

  __shared__ __align__(16) _Float16 hh[3][NS][64];          // h rings
  __shared__ __align__(16) float pj[2][NS][256];            // proj rings
  __shared__ __align__(16) unsigned char wlds[3][256 * 80]; // streamed W halves
  __shared__ float xs[TT];
  __shared__ int prog[8];                                   // per-wave windows done

  for (int i = tid; i < TT; i += 512) xs[i] = x[(size_t)b * TT + i];
  for (int i = tid; i < 3 * NS * 64 / 2; i += 512) reinterpret_cast<int*>(hh)[i] = 0;
  if (tid < 8) prog[tid] = 0;

  v2h wt[4][16];
  float bias[4] = {0.f, 0.f, 0.f, 0.f};
  float wi0_[4] = {0.f, 0.f, 0.f, 0.f};
  float whb0[4] = {}, wi1b[4] = {}, wh1b[4] = {}, bb1[4] = {},
        wi2b[4] = {}, wh2b[4] = {}, bb2[4] = {};

  if (wave == 0) {  // a0 recurrence
    load_rec_w(whh_a0, lane, wt, &wlds[0][0]);
#pragma unroll
    for (int q = 0; q < 4; ++q) {
      const int row = q * 64 + lane;
      bias[q] = bih_a0[row] + bhh_a0[row];
      wi0_[q] = wih_a0[row];
    }
    PIN16(wt[0]); PIN16(wt[1]); PIN16(wt[2]); PIN16(wt[3]);
  } else if (wave == 1) {  // a1 recurrence
    load_rec_w(whh_a1, lane, wt, &wlds[1][0]);
#pragma unroll
    for (int q = 0; q < 4; ++q) bias[q] = bih_a1[q * 64 + lane] + bhh_a1[q * 64 + lane];
    PIN16(wt[0]); PIN16(wt[1]); PIN16(wt[2]); PIN16(wt[3]);
  } else if (wave == 2) {  // a2 recurrence
    load_rec_w(whh_a2, lane, wt, &wlds[2][0]);
#pragma unroll
    for (int q = 0; q < 4; ++q) bias[q] = bih_a2[q * 64 + lane] + bhh_a2[q * 64 + lane];
    PIN16(wt[0]); PIN16(wt[1]); PIN16(wt[2]); PIN16(wt[3]);
  } else if (wave == 3) {  // b-chain: one row of wih_b0 in wt[0](lo)/wt[1](hi)
    const int q = lane & 3;
    load_row_pair(wih_b0 + q * 64, wt[0], wt[1]);
    bias[0] = bih_b0[q] + bhh_b0[q];
#pragma unroll
    for (int k = 0; k < 4; ++k) {
      whb0[k] = whh_b0[k];
      wi1b[k] = wih_b1[k]; wh1b[k] = whh_b1[k]; bb1[k] = bih_b1[k] + bhh_b1[k];
      wi2b[k] = wih_b2[k]; wh2b[k] = whh_b2[k]; bb2[k] = bih_b2[k] + bhh_b2[k];
    }
    PIN16(wt[0]); PIN16(wt[1]);
  } else if (wave == 4) {  // a1 proj gates 0,1
    load_row_pair(wih_a1 + (0 * 64 + lane) * 64, wt[0], wt[1]);
    load_row_pair(wih_a1 + (1 * 64 + lane) * 64, wt[2], wt[3]);
    PIN16(wt[0]); PIN16(wt[1]); PIN16(wt[2]); PIN16(wt[3]);
  } else if (wave == 5) {  // a1 proj gates 2,3
    load_row_pair(wih_a1 + (2 * 64 + lane) * 64, wt[0], wt[1]);
    load_row_pair(wih_a1 + (3 * 64 + lane) * 64, wt[2], wt[3]);
    PIN16(wt[0]); PIN16(wt[1]); PIN16(wt[2]); PIN16(wt[3]);
  } else if (wave == 6) {  // a2 proj gates 0,1
    load_row_pair(wih_a2 + (0 * 64 + lane) * 64, wt[0], wt[1]);
    load_row_pair(wih_a2 + (1 * 64 + lane) * 64, wt[2], wt[3]);
    PIN16(wt[0]); PIN16(wt[1]); PIN16(wt[2]); PIN16(wt[3]);
  } else {                 // a2 proj gates 2,3
    load_row_pair(wih_a2 + (2 * 64 + lane) * 64, wt[0], wt[1]);
    load_row_pair(wih_a2 + (3 * 64 + lane) * 64, wt[2], wt[3]);
    PIN16(wt[0]); PIN16(wt[1]); PIN16(wt[2]); PIN16(wt[3]);
  }
  __syncthreads();

  float c = 0.f;
  float h0b = 0.f, c0b = 0.f, h1b = 0.f, c1b = 0.f, h2b = 0.f, c2b = 0.f;

  if (wave == 0) {  // a0 rec -> hh[0]; ring consumers w4,w5
    __builtin_amdgcn_s_setprio(1);
    for (int k = 0; k < NW; ++k) {
      if (k >= 2) { WAITP(4, k - 1); WAITP(5, k - 1); }
      const int t0 = k * CH;
      for (int s = 0; s < CH; ++s) {
        const int t = t0 + s;
        v2h hv[32];
        load_h64(&hh[0][(t + NS - 1) & (NS - 1)][0], hv);
        const float xv = xs[t];
        float p0 = bias[0], p1 = bias[1], p2 = bias[2], p3 = bias[3];
        dot4full_(wt, &wlds[0][0], lane, hv, p0, p1, p2, p3);
        p0 = __builtin_fmaf(wi0_[0], xv, p0);
        p1 = __builtin_fmaf(wi0_[1], xv, p1);
        p2 = __builtin_fmaf(wi0_[2], xv, p2);
        p3 = __builtin_fmaf(wi0_[3], xv, p3);
        float gi = sig_(p0), gf = sig_(p1), gg = tanh_(p2), go = sig_(p3);
        c = __builtin_fmaf(gf, c, gi * gg);
        hh[0][t & (NS - 1)][lane] = (_Float16)(go * tanh_(c));
      }
      POSTP(0, k + 1);
    }
    __builtin_amdgcn_s_setprio(0);
  } else if (wave == 1) {  // a1 rec: reads pj[0]; -> hh[1]; ring consumers w6,w7
    __builtin_amdgcn_s_setprio(1);
    for (int k = 0; k < NW; ++k) {
      WAITP(4, k + 1); WAITP(5, k + 1);
      if (k >= 2) { WAITP(6, k - 1); WAITP(7, k - 1); }
      const int t0 = k * CH;
      for (int s = 0; s < CH; ++s) {
        const int t = t0 + s;
        v2h hv[32];
        load_h64(&hh[1][(t + NS - 1) & (NS - 1)][0], hv);
        float4 pr = *reinterpret_cast<const float4*>(&pj[0][t & (NS - 1)][lane * 4]);
        float p0 = bias[0], p1 = bias[1], p2 = bias[2], p3 = bias[3];
        dot4full_(wt, &wlds[1][0], lane, hv, p0, p1, p2, p3);
        p0 += pr.x; p1 += pr.y; p2 += pr.z; p3 += pr.w;
        float gi = sig_(p0), gf = sig_(p1), gg = tanh_(p2), go = sig_(p3);
        c = __builtin_fmaf(gf, c, gi * gg);
        hh[1][t & (NS - 1)][lane] = (_Float16)(go * tanh_(c));
      }
      POSTP(1, k + 1);
    }
    __builtin_amdgcn_s_setprio(0);
  } else if (wave == 2) {  // a2 rec: reads pj[1]; -> hh[2]; ring consumer w3
    __builtin_amdgcn_s_setprio(1);
    for (int k = 0; k < NW; ++k) {
      WAITP(6, k + 1); WAITP(7, k + 1);
      if (k >= 2) { WAITP(3, k - 1); }
      const int t0 = k * CH;
      for (int s = 0; s < CH; ++s) {
        const int t = t0 + s;
        v2h hv[32];
        load_h64(&hh[2][(t + NS - 1) & (NS - 1)][0], hv);
        float4 pr = *reinterpret_cast<const float4*>(&pj[1][t & (NS - 1)][lane * 4]);
        float p0 = bias[0], p1 = bias[1], p2 = bias[2], p3 = bias[3];
        dot4full_(wt, &wlds[2][0], lane, hv, p0, p1, p2, p3);
        p0 += pr.x; p1 += pr.y; p2 += pr.z; p3 += pr.w;
        float gi = sig_(p0), gf = sig_(p1), gg = tanh_(p2), go = sig_(p3);
        c = __builtin_fmaf(gf, c, gi * gg);
        hh[2][t & (NS - 1)][lane] = (_Float16)(go * tanh_(c));
      }
      POSTP(2, k + 1);
    }
    __builtin_amdgcn_s_setprio(0);
  } else if (wave == 3) {  // b-chain: reads hh[2]
    for (int k = 0; k < NW; ++k) {
      WAITP(2, k + 1);
      const int t0 = k * CH;
      for (int s = 0; s < CH; ++s) {
        const int t = t0 + s;
        v2h hv[32];
        load_h64(&hh[2][t & (NS - 1)][0], hv);
        float pga = bias[0], pgb = 0.f;
#pragma unroll
        for (int j = 0; j < 16; ++j) {
          FDOT2(pga, wt[0][j], hv[j]);
          FDOT2(pgb, wt[1][j], hv[16 + j]);
        }
        float pg = pga + pgb;
        float p_i = qb_<0>(pg), p_f = qb_<1>(pg), p_g = qb_<2>(pg), p_o = qb_<3>(pg);
        float i0 = sig_(__builtin_fmaf(whb0[0], h0b, p_i));
        float f0 = sig_(__builtin_fmaf(whb0[1], h0b, p_f));
        float g0 = tanh_(__builtin_fmaf(whb0[2], h0b, p_g));
        float o0 = sig_(__builtin_fmaf(whb0[3], h0b, p_o));
        c0b = __builtin_fmaf(f0, c0b, i0 * g0);
        h0b = o0 * tanh_(c0b);
        float i1 = sig_(bb1[0] + __builtin_fmaf(wi1b[0], h0b, wh1b[0] * h1b));
        float f1 = sig_(bb1[1] + __builtin_fmaf(wi1b[1], h0b, wh1b[1] * h1b));
        float g1 = tanh_(bb1[2] + __builtin_fmaf(wi1b[2], h0b, wh1b[2] * h1b));
        float o1 = sig_(bb1[3] + __builtin_fmaf(wi1b[3], h0b, wh1b[3] * h1b));
        c1b = __builtin_fmaf(f1, c1b, i1 * g1);
        h1b = o1 * tanh_(c1b);
        float i2 = sig_(bb2[0] + __builtin_fmaf(wi2b[0], h1b, wh2b[0] * h2b));
        float f2 = sig_(bb2[1] + __builtin_fmaf(wi2b[1], h1b, wh2b[1] * h2b));
        float g2 = tanh_(bb2[2] + __builtin_fmaf(wi2b[2], h1b, wh2b[2] * h2b));
        float o2 = sig_(bb2[3] + __builtin_fmaf(wi2b[3], h1b, wh2b[3] * h2b));
        c2b = __builtin_fmaf(f2, c2b, i2 * g2);
        h2b = o2 * tanh_(c2b);
        if (lane == 0) out[(size_t)b * TT + t] = h2b;
      }
      POSTP(3, k + 1);
    }
  } else if (wave == 4) {  // a1 proj g01: reads hh[0]; -> pj[0].xy; consumer w1
    for (int k = 0; k < NW; ++k) {
      WAITP(0, k + 1);
      if (k >= 2) { WAITP(1, k - 1); }
      const int t0 = k * CH;
      for (int s = 0; s < CH; ++s) {
        const int t = t0 + s;
        v2h hv[32];
        load_h64(&hh[0][t & (NS - 1)][0], hv);
        float p0, p1;
        dot2g_(wt[0], wt[1], wt[2], wt[3], hv, p0, p1);
        *reinterpret_cast<float2*>(&pj[0][t & (NS - 1)][lane * 4]) = float2{p0, p1};
      }
      POSTP(4, k + 1);
    }
  } else if (wave == 5) {  // a1 proj g23
    for (int k = 0; k < NW; ++k) {
      WAITP(0, k + 1);
      if (k >= 2) { WAITP(1, k - 1); }
      const int t0 = k * CH;
      for (int s = 0; s < CH; ++s) {
        const int t = t0 + s;
        v2h hv[32];
        load_h64(&hh[0][t & (NS - 1)][0], hv);
        float p2, p3;
        dot2g_(wt[0], wt[1], wt[2], wt[3], hv, p2, p3);
        *reinterpret_cast<float2*>(&pj[0][t & (NS - 1)][lane * 4 + 2]) = float2{p2, p3};
      }
      POSTP(5, k + 1);
    }
  } else if (wave == 6) {  // a2 proj g01: reads hh[1]; -> pj[1].xy; consumer w2
    for (int k = 0; k < NW; ++k) {
      WAITP(1, k + 1);
      if (k >= 2) { WAITP(2, k - 1); }
      const int t0 = k * CH;
      for (int s = 0; s < CH; ++s) {
        const int t = t0 + s;
        v2h hv[32];
        load_h64(&hh[1][t & (NS - 1)][0], hv);
        float p0, p1;
        dot2g_(wt[0], wt[1], wt[2], wt[3], hv, p0, p1);
        *reinterpret_cast<float2*>(&pj[1][t & (NS - 1)][lane * 4]) = float2{p0, p1};
      }
      POSTP(6, k + 1);
    }
  } else {                 // a2 proj g23
    for (int k = 0; k < NW; ++k) {
      WAITP(1, k + 1);
      if (k >= 2) { WAITP(2, k - 1); }
      const int t0 = k * CH;
      for (int s = 0; s < CH; ++s) {
        const int t = t0 + s;
        v2h hv[32];
        load_h64(&hh[1][t & (NS - 1)][0], hv);
        float p2, p3;
        dot2g_(wt[0], wt[1], wt[2], wt[3], hv, p2, p3);
        *reinterpret_cast<float2*>(&pj[1][t & (NS - 1)][lane * 4 + 2]) = float2{p2, p3};
      }
      POSTP(7, k + 1);
    }
  }
}

extern "C" void kernel_launch(void* const* d_in, const int* in_sizes, int n_in,
                              void* d_out, int out_size, void* d_ws, size_t ws_size,
                              hipStream_t stream) {
  const float* x      = (const float*)d_in[0];
  const float* wih_a0 = (const float*)d_in[1];
  const float* whh_a0 = (const float*)d_in[2];
  const float* bih_a0 = (const float*)d_in[3];
  const float* bhh_a0 = (const float*)d_in[4];
  const float* wih_a1 = (const float*)d_in[5];
  const float* whh_a1 = (const float*)d_in[6];
  const float* bih_a1 = (const float*)d_in[7];
  const float* bhh_a1 = (const float*)d_in[8];
  const float* wih_a2 = (const float*)d_in[9];
  const float* whh_a2 = (const float*)d_in[10];
  const float* bih_a2 = (const float*)d_in[11];
  const float* bhh_a2 = (const float*)d_in[12];
  const float* wih_b0 = (const float*)d_in[13];
  const float* whh_b0 = (const float*)d_in[14];
  const float* bih_b0 = (const float*)d_in[15];
  const float* bhh_b0 = (const float*)d_in[16];
  const float* wih_b1 = (const float*)d_in[17];
  const float* whh_b1 = (const float*)d_in[18];
  const float* bih_b1 = (const float*)d_in[19];
  const float* bhh_b1 = (const float*)d_in[20];
  const float* wih_b2 = (const float*)d_in[21];
  const float* whh_b2 = (const float*)d_in[22];
  const float* bih_b2 = (const float*)d_in[23];
  const float* bhh_b2 = (const float*)d_in[24];
  float* out = (float*)d_out;

  lstm_pipe_k<<<BB, 512, 0, stream>>>(
      x,
      wih_a0, whh_a0, bih_a0, bhh_a0,
      wih_a1, whh_a1, bih_a1, bhh_a1,
      wih_a2, whh_a2, bih_a2, bhh_a2,
      wih_b0, whh_b0, bih_b0, bhh_b0,
      wih_b1, whh_b1, bih_b1, bhh_b1,
      wih_b2, whh_b2, bih_b2, bhh_b2,
      out);
}